// Round 1
// baseline (2250.686 us; speedup 1.0000x reference)
//
#include <hip/hip_runtime.h>
#include <cstddef>

#define NN 50000
#define EE 800000

// ---- order-preserving float<->uint key for atomicMax-based segment max ----
__device__ __forceinline__ unsigned int fkey(float f) {
  unsigned int u = __float_as_uint(f);
  return (u & 0x80000000u) ? ~u : (u | 0x80000000u);
}
__device__ __forceinline__ float funkey(unsigned int k) {
  return (k & 0x80000000u) ? __uint_as_float(k & 0x7FFFFFFFu) : __uint_as_float(~k);
}
__device__ __forceinline__ float leaky(float x) { return x >= 0.f ? x : 0.2f * x; }

// ---- C[n,m] = sum_k A[n,k]*B[k,m]; 64x64 tile, TK=16, 256 thr, 4x4/thread ----
__global__ __launch_bounds__(256) void gemm_k(const float* __restrict__ A,
                                              const float* __restrict__ B,
                                              float* __restrict__ C,
                                              int K, int M) {
  __shared__ float As[16][68];  // [k][n], +4 pad keeps float4 alignment, breaks pow2 stride
  __shared__ float Bs[16][68];  // [k][m]
  const int tid = threadIdx.x;
  const int bn = blockIdx.x * 64;
  const int bm = blockIdx.y * 64;
  const int tx = tid & 15;
  const int ty = tid >> 4;
  const int la_row = tid >> 2;
  const int la_k4 = (tid & 3) << 2;
  const int lb_k = tid >> 4;
  const int lb_m4 = (tid & 15) << 2;
  float acc[4][4] = {};
  for (int k0 = 0; k0 < K; k0 += 16) {
    float4 av = make_float4(0.f, 0.f, 0.f, 0.f);
    int ar = bn + la_row;
    if (ar < NN) av = *(const float4*)(A + (size_t)ar * K + (k0 + la_k4));
    As[la_k4 + 0][la_row] = av.x;
    As[la_k4 + 1][la_row] = av.y;
    As[la_k4 + 2][la_row] = av.z;
    As[la_k4 + 3][la_row] = av.w;
    *(float4*)&Bs[lb_k][lb_m4] = *(const float4*)(B + (size_t)(k0 + lb_k) * M + (bm + lb_m4));
    __syncthreads();
#pragma unroll
    for (int k = 0; k < 16; ++k) {
      float4 a = *(float4*)&As[k][ty << 2];
      float4 b = *(float4*)&Bs[k][tx << 2];
      acc[0][0] += a.x * b.x; acc[0][1] += a.x * b.y; acc[0][2] += a.x * b.z; acc[0][3] += a.x * b.w;
      acc[1][0] += a.y * b.x; acc[1][1] += a.y * b.y; acc[1][2] += a.y * b.z; acc[1][3] += a.y * b.w;
      acc[2][0] += a.z * b.x; acc[2][1] += a.z * b.y; acc[2][2] += a.z * b.z; acc[2][3] += a.z * b.w;
      acc[3][0] += a.w * b.x; acc[3][1] += a.w * b.y; acc[3][2] += a.w * b.z; acc[3][3] += a.w * b.w;
    }
    __syncthreads();
  }
#pragma unroll
  for (int i = 0; i < 4; ++i) {
    int r = bn + (ty << 2) + i;
    if (r < NN)
      *(float4*)(C + (size_t)r * M + bm + (tx << 2)) =
          make_float4(acc[i][0], acc[i][1], acc[i][2], acc[i][3]);
  }
}

// ---- alpha_s/alpha_d: one wave per (node, head), 64-lane dot + shfl reduce ----
__global__ __launch_bounds__(256) void alpha_k(const float* __restrict__ h,
                                               const float* __restrict__ a_s,
                                               const float* __restrict__ a_d,
                                               float* __restrict__ als,
                                               float* __restrict__ ald,
                                               int H, int Hsh) {
  int gid = blockIdx.x * 256 + threadIdx.x;
  int wid = gid >> 6;
  int lane = gid & 63;
  if (wid >= NN * H) return;
  int hh = wid & (H - 1);
  int n = wid >> Hsh;
  float hv = h[(size_t)n * (H << 6) + (hh << 6) + lane];
  float va = hv * a_s[(hh << 6) + lane];
  float vd = hv * a_d[(hh << 6) + lane];
#pragma unroll
  for (int off = 32; off; off >>= 1) {
    va += __shfl_xor(va, off, 64);
    vd += __shfl_xor(vd, off, 64);
  }
  if (lane == 0) { als[wid] = va; ald[wid] = vd; }
}

__global__ __launch_bounds__(256) void edge_max_k(const int* __restrict__ ei,
                                                  const float* __restrict__ als,
                                                  const float* __restrict__ ald,
                                                  unsigned int* __restrict__ mkey,
                                                  int H, int Hsh) {
  int i = blockIdx.x * 256 + threadIdx.x;
  if (i >= (EE + NN) * H) return;
  int e = i >> Hsh, hh = i & (H - 1);
  int src, dst;
  if (e < EE) { src = ei[e]; dst = ei[EE + e]; } else { src = dst = e - EE; }
  float x = als[src * H + hh] + ald[dst * H + hh];
  atomicMax(&mkey[dst * H + hh], fkey(leaky(x)));
}

__global__ __launch_bounds__(256) void edge_sum_k(const int* __restrict__ ei,
                                                  const float* __restrict__ als,
                                                  const float* __restrict__ ald,
                                                  const unsigned int* __restrict__ mkey,
                                                  float* __restrict__ den,
                                                  int H, int Hsh) {
  int i = blockIdx.x * 256 + threadIdx.x;
  if (i >= (EE + NN) * H) return;
  int e = i >> Hsh, hh = i & (H - 1);
  int src, dst;
  if (e < EE) { src = ei[e]; dst = ei[EE + e]; } else { src = dst = e - EE; }
  int ih = dst * H + hh;
  float x = als[src * H + hh] + ald[ih];
  atomicAdd(&den[ih], __expf(leaky(x) - funkey(mkey[ih])));
}

// one block per edge; thread t -> (head = t>>6, channel = t&63)
__global__ void edge_aggr_k(const int* __restrict__ ei,
                            const float* __restrict__ als,
                            const float* __restrict__ ald,
                            const unsigned int* __restrict__ mkey,
                            const float* __restrict__ den,
                            const float* __restrict__ h,
                            float* __restrict__ out, int H) {
  int e = blockIdx.x;
  int t = threadIdx.x;
  int hh = t >> 6;
  int src, dst;
  if (e < EE) { src = ei[e]; dst = ei[EE + e]; } else { src = dst = e - EE; }
  int ih = dst * H + hh;
  float x = als[src * H + hh] + ald[ih];
  float alpha = __expf(leaky(x) - funkey(mkey[ih])) / (den[ih] + 1e-16f);
  int F = H << 6;
  atomicAdd(&out[(size_t)dst * F + t], alpha * h[(size_t)src * F + t]);
}

__global__ __launch_bounds__(256) void bias_act_k(float* __restrict__ out,
                                                  const float* __restrict__ b,
                                                  int F, int Fmask, int do_relu) {
  int i = blockIdx.x * 256 + threadIdx.x;
  if (i >= NN * F) return;
  float v = out[i] + b[i & Fmask];
  out[i] = do_relu ? fmaxf(v, 0.f) : v;
}

// column sums of h2 [N,64] -> g[64] (as sums; divided by N in head_k)
__global__ __launch_bounds__(256) void colsum_k(const float* __restrict__ h2,
                                                float* __restrict__ g) {
  __shared__ float s[256];
  int tid = threadIdx.x;
  int c = tid & 63, rg = tid >> 6;
  float acc = 0.f;
  for (int n = blockIdx.x * 4 + rg; n < NN; n += gridDim.x * 4)
    acc += h2[n * 64 + c];
  s[tid] = acc;
  __syncthreads();
  if (tid < 64) atomicAdd(&g[c], s[c] + s[64 + c] + s[128 + c] + s[192 + c]);
}

__global__ void head_k(const float* __restrict__ g, const float* __restrict__ hw,
                       const float* __restrict__ hb, float* __restrict__ out) {
  int o = threadIdx.x;  // 64 threads
  float acc = 0.f;
  const float invN = 1.0f / (float)NN;
#pragma unroll 8
  for (int c = 0; c < 64; ++c) acc += (g[c] * invN) * hw[c * 64 + o];
  out[o] = acc + hb[o];
}

extern "C" void kernel_launch(void* const* d_in, const int* in_sizes, int n_in,
                              void* d_out, int out_size, void* d_ws, size_t ws_size,
                              hipStream_t stream) {
  const float* x   = (const float*)d_in[0];
  const int*   ei  = (const int*)d_in[1];
  const float* W0  = (const float*)d_in[2];
  const float* a0s = (const float*)d_in[3];
  const float* a0d = (const float*)d_in[4];
  const float* b0  = (const float*)d_in[5];
  const float* W1  = (const float*)d_in[6];
  const float* a1s = (const float*)d_in[7];
  const float* a1d = (const float*)d_in[8];
  const float* b1  = (const float*)d_in[9];
  const float* W2  = (const float*)d_in[10];
  const float* a2s = (const float*)d_in[11];
  const float* a2d = (const float*)d_in[12];
  const float* b2  = (const float*)d_in[13];
  const float* hw  = (const float*)d_in[14];
  const float* hb  = (const float*)d_in[15];
  float* out = (float*)d_out;

  char* w = (char*)d_ws;
  float* bufA = (float*)w;               w += (size_t)NN * 256 * 4;  // h (pre-attention)
  float* bufB = (float*)w;               w += (size_t)NN * 256 * 4;  // layer output
  float* als  = (float*)w;               w += (size_t)NN * 4 * 4;
  float* ald  = (float*)w;               w += (size_t)NN * 4 * 4;
  unsigned int* mkey = (unsigned int*)w; w += (size_t)NN * 4 * 4;
  float* den  = (float*)w;               w += (size_t)NN * 4 * 4;
  float* g    = (float*)w;               w += 256;

  auto run_layer = [&](const float* in, int K, const float* W, const float* a_s,
                       const float* a_d, const float* bias, int H, int Hsh,
                       float* hbuf, float* obuf, int do_relu) {
    int F = H * 64;
    dim3 gg((NN + 63) / 64, F / 64);
    gemm_k<<<gg, 256, 0, stream>>>(in, W, hbuf, K, F);
    alpha_k<<<(NN * H * 64 + 255) / 256, 256, 0, stream>>>(hbuf, a_s, a_d, als, ald, H, Hsh);
    hipMemsetAsync(mkey, 0, (size_t)NN * H * 4, stream);
    hipMemsetAsync(den, 0, (size_t)NN * H * 4, stream);
    hipMemsetAsync(obuf, 0, (size_t)NN * F * 4, stream);
    int etot = (EE + NN) * H;
    edge_max_k<<<(etot + 255) / 256, 256, 0, stream>>>(ei, als, ald, mkey, H, Hsh);
    edge_sum_k<<<(etot + 255) / 256, 256, 0, stream>>>(ei, als, ald, mkey, den, H, Hsh);
    edge_aggr_k<<<EE + NN, F, 0, stream>>>(ei, als, ald, mkey, den, hbuf, obuf, H);
    bias_act_k<<<(NN * F + 255) / 256, 256, 0, stream>>>(obuf, bias, F, F - 1, do_relu);
  };

  // layer 0: x[N,128] -> bufB[N,256], relu
  run_layer(x, 128, W0, a0s, a0d, b0, 4, 2, bufA, bufB, 1);
  // layer 1: bufB[N,256] -> bufB[N,256], relu (h in bufA; gemm input consumed before obuf memset)
  run_layer(bufB, 256, W1, a1s, a1d, b1, 4, 2, bufA, bufB, 1);
  // layer 2: bufB[N,256] -> bufB[N,64], no relu
  run_layer(bufB, 256, W2, a2s, a2d, b2, 1, 0, bufA, bufB, 0);

  hipMemsetAsync(g, 0, 64 * 4, stream);
  colsum_k<<<256, 256, 0, stream>>>(bufB, g);
  head_k<<<1, 64, 0, stream>>>(g, hw, hb, out);
}

// Round 2
// 973.629 us; speedup vs baseline: 2.3116x; 2.3116x over previous
//
#include <hip/hip_runtime.h>
#include <cstddef>

#define NN 50000
#define EE 800000
#define NB ((NN + 255) / 256)

__device__ __forceinline__ float leaky(float x) { return x >= 0.f ? x : 0.2f * x; }

// ---- C[n,m] = sum_k A[n,k]*B[k,m]; 64x64 tile, TK=16, 256 thr, 4x4/thread ----
__global__ __launch_bounds__(256) void gemm_k(const float* __restrict__ A,
                                              const float* __restrict__ B,
                                              float* __restrict__ C,
                                              int K, int M) {
  __shared__ float As[16][68];
  __shared__ float Bs[16][68];
  const int tid = threadIdx.x;
  const int bn = blockIdx.x * 64;
  const int bm = blockIdx.y * 64;
  const int tx = tid & 15;
  const int ty = tid >> 4;
  const int la_row = tid >> 2;
  const int la_k4 = (tid & 3) << 2;
  const int lb_k = tid >> 4;
  const int lb_m4 = (tid & 15) << 2;
  float acc[4][4] = {};
  for (int k0 = 0; k0 < K; k0 += 16) {
    float4 av = make_float4(0.f, 0.f, 0.f, 0.f);
    int ar = bn + la_row;
    if (ar < NN) av = *(const float4*)(A + (size_t)ar * K + (k0 + la_k4));
    As[la_k4 + 0][la_row] = av.x;
    As[la_k4 + 1][la_row] = av.y;
    As[la_k4 + 2][la_row] = av.z;
    As[la_k4 + 3][la_row] = av.w;
    *(float4*)&Bs[lb_k][lb_m4] = *(const float4*)(B + (size_t)(k0 + lb_k) * M + (bm + lb_m4));
    __syncthreads();
#pragma unroll
    for (int k = 0; k < 16; ++k) {
      float4 a = *(float4*)&As[k][ty << 2];
      float4 b = *(float4*)&Bs[k][tx << 2];
      acc[0][0] += a.x * b.x; acc[0][1] += a.x * b.y; acc[0][2] += a.x * b.z; acc[0][3] += a.x * b.w;
      acc[1][0] += a.y * b.x; acc[1][1] += a.y * b.y; acc[1][2] += a.y * b.z; acc[1][3] += a.y * b.w;
      acc[2][0] += a.z * b.x; acc[2][1] += a.z * b.y; acc[2][2] += a.z * b.z; acc[2][3] += a.z * b.w;
      acc[3][0] += a.w * b.x; acc[3][1] += a.w * b.y; acc[3][2] += a.w * b.z; acc[3][3] += a.w * b.w;
    }
    __syncthreads();
  }
#pragma unroll
  for (int i = 0; i < 4; ++i) {
    int r = bn + (ty << 2) + i;
    if (r < NN)
      *(float4*)(C + (size_t)r * M + bm + (tx << 2)) =
          make_float4(acc[i][0], acc[i][1], acc[i][2], acc[i][3]);
  }
}

// ---- alpha_s/alpha_d: one wave per (node, head), 64-lane dot + shfl reduce ----
__global__ __launch_bounds__(256) void alpha_k(const float* __restrict__ h,
                                               const float* __restrict__ a_s,
                                               const float* __restrict__ a_d,
                                               float* __restrict__ als,
                                               float* __restrict__ ald,
                                               int H, int Hsh) {
  int gid = blockIdx.x * 256 + threadIdx.x;
  int wid = gid >> 6;
  int lane = gid & 63;
  if (wid >= NN * H) return;
  int hh = wid & (H - 1);
  int n = wid >> Hsh;
  float hv = h[(size_t)n * (H << 6) + (hh << 6) + lane];
  float va = hv * a_s[(hh << 6) + lane];
  float vd = hv * a_d[(hh << 6) + lane];
#pragma unroll
  for (int off = 32; off; off >>= 1) {
    va += __shfl_xor(va, off, 64);
    vd += __shfl_xor(vd, off, 64);
  }
  if (lane == 0) { als[wid] = va; ald[wid] = vd; }
}

// ================= CSR build (topology is layer-invariant; built once/call) ==
__global__ __launch_bounds__(256) void hist_k(const int* __restrict__ ei, int* deg) {
  int i = blockIdx.x * 256 + threadIdx.x;
  if (i < EE) atomicAdd(&deg[ei[EE + i]], 1);
}

__global__ __launch_bounds__(256) void scan1_k(const int* __restrict__ deg,
                                               int* __restrict__ incl,
                                               int* __restrict__ partial) {
  __shared__ int s[256];
  int t = threadIdx.x;
  int i = blockIdx.x * 256 + t;
  int v = (i < NN) ? deg[i] : 0;
  s[t] = v;
  __syncthreads();
  for (int off = 1; off < 256; off <<= 1) {
    int u = (t >= off) ? s[t - off] : 0;
    __syncthreads();
    s[t] += u;
    __syncthreads();
  }
  if (i < NN) incl[i] = s[t];
  if (t == 255) partial[blockIdx.x] = s[255];
}

__global__ void scan2_k(int* __restrict__ partial) {
  __shared__ int s[256];
  int t = threadIdx.x;
  int v = (t < NB) ? partial[t] : 0;
  s[t] = v;
  __syncthreads();
  for (int off = 1; off < 256; off <<= 1) {
    int u = (t >= off) ? s[t - off] : 0;
    __syncthreads();
    s[t] += u;
    __syncthreads();
  }
  if (t < NB) partial[t] = s[t] - v;  // exclusive
}

__global__ __launch_bounds__(256) void scan3_k(const int* __restrict__ deg,
                                               const int* __restrict__ incl,
                                               const int* __restrict__ partial,
                                               int* __restrict__ rowptr,
                                               int* __restrict__ cursor) {
  int i = blockIdx.x * 256 + threadIdx.x;
  if (i >= NN) return;
  int r = partial[blockIdx.x] + incl[i] - deg[i];
  rowptr[i] = r;
  cursor[i] = r;
}

__global__ __launch_bounds__(256) void scatter_k(const int* __restrict__ ei,
                                                 int* __restrict__ cursor,
                                                 int* __restrict__ csr_src) {
  int i = blockIdx.x * 256 + threadIdx.x;
  if (i >= EE) return;
  int d = ei[EE + i];
  int p = atomicAdd(&cursor[d], 1);
  csr_src[p] = ei[i];
}

// ====== fused segment-softmax + aggregation: one block/dst, one wave/head ====
// self-loop handled explicitly (not stored in CSR). Zero atomics.
__global__ void gat_aggr_k(const int* __restrict__ rowptr, const int* __restrict__ deg,
                           const int* __restrict__ csr_src,
                           const float* __restrict__ als, const float* __restrict__ ald,
                           const float* __restrict__ h, const float* __restrict__ bias,
                           float* __restrict__ out, int H, int do_relu) {
  int dst = blockIdx.x;
  int t = threadIdx.x;
  int head = t >> 6;
  int lane = t & 63;
  int F = H << 6;
  int rs = rowptr[dst];
  int dg = deg[dst];
  float aldv = ald[dst * H + head];
  float xself = leaky(als[dst * H + head] + aldv);

  // phase A: segment max (lane-parallel over edges)
  float m = xself;
  for (int j = lane; j < dg; j += 64) {
    int s = csr_src[rs + j];
    m = fmaxf(m, leaky(als[s * H + head] + aldv));
  }
#pragma unroll
  for (int off = 32; off; off >>= 1) m = fmaxf(m, __shfl_xor(m, off, 64));

  // phase B: segment sum of exp
  float ssum = 0.f;
  for (int j = lane; j < dg; j += 64) {
    int s = csr_src[rs + j];
    ssum += __expf(leaky(als[s * H + head] + aldv) - m);
  }
#pragma unroll
  for (int off = 32; off; off >>= 1) ssum += __shfl_xor(ssum, off, 64);
  ssum += __expf(xself - m);
  float inv = 1.f / (ssum + 1e-16f);

  // phase C: weighted aggregation (lane = channel, serial over edges)
  size_t hbase = (size_t)(head << 6) + lane;
  float acc = __expf(xself - m) * inv * h[(size_t)dst * F + hbase];
  for (int j = 0; j < dg; ++j) {
    int s = csr_src[rs + j];
    float a = __expf(leaky(als[s * H + head] + aldv) - m) * inv;
    acc += a * h[(size_t)s * F + hbase];
  }
  float v = acc + bias[t];
  out[(size_t)dst * F + t] = do_relu ? fmaxf(v, 0.f) : v;
}

// column sums of h2 [N,64] -> g[64]
__global__ __launch_bounds__(256) void colsum_k(const float* __restrict__ h2,
                                                float* __restrict__ g) {
  __shared__ float s[256];
  int tid = threadIdx.x;
  int c = tid & 63, rg = tid >> 6;
  float acc = 0.f;
  for (int n = blockIdx.x * 4 + rg; n < NN; n += gridDim.x * 4)
    acc += h2[n * 64 + c];
  s[tid] = acc;
  __syncthreads();
  if (tid < 64) atomicAdd(&g[c], s[c] + s[64 + c] + s[128 + c] + s[192 + c]);
}

__global__ void head_k(const float* __restrict__ g, const float* __restrict__ hw,
                       const float* __restrict__ hb, float* __restrict__ out) {
  int o = threadIdx.x;  // 64 threads
  float acc = 0.f;
  const float invN = 1.0f / (float)NN;
#pragma unroll 8
  for (int c = 0; c < 64; ++c) acc += (g[c] * invN) * hw[c * 64 + o];
  out[o] = acc + hb[o];
}

extern "C" void kernel_launch(void* const* d_in, const int* in_sizes, int n_in,
                              void* d_out, int out_size, void* d_ws, size_t ws_size,
                              hipStream_t stream) {
  const float* x   = (const float*)d_in[0];
  const int*   ei  = (const int*)d_in[1];
  const float* W0  = (const float*)d_in[2];
  const float* a0s = (const float*)d_in[3];
  const float* a0d = (const float*)d_in[4];
  const float* b0  = (const float*)d_in[5];
  const float* W1  = (const float*)d_in[6];
  const float* a1s = (const float*)d_in[7];
  const float* a1d = (const float*)d_in[8];
  const float* b1  = (const float*)d_in[9];
  const float* W2  = (const float*)d_in[10];
  const float* a2s = (const float*)d_in[11];
  const float* a2d = (const float*)d_in[12];
  const float* b2  = (const float*)d_in[13];
  const float* hw  = (const float*)d_in[14];
  const float* hb  = (const float*)d_in[15];
  float* out = (float*)d_out;

  char* w = (char*)d_ws;
  float* bufA = (float*)w;    w += (size_t)NN * 256 * 4;  // h (pre-attention)
  float* bufB = (float*)w;    w += (size_t)NN * 256 * 4;  // layer output
  float* als  = (float*)w;    w += (size_t)NN * 4 * 4;
  float* ald  = (float*)w;    w += (size_t)NN * 4 * 4;
  int* deg     = (int*)w;     w += (size_t)NN * 4;
  int* rowptr  = (int*)w;     w += (size_t)NN * 4;
  int* cursor  = (int*)w;     w += (size_t)NN * 4;
  int* incl    = (int*)w;     w += (size_t)NN * 4;
  int* partial = (int*)w;     w += 256 * 4;
  int* csr_src = (int*)w;     w += (size_t)EE * 4;
  float* g    = (float*)w;    w += 256;

  // ---- build CSR once (shared by all 3 layers) ----
  hipMemsetAsync(deg, 0, (size_t)NN * 4, stream);
  hist_k<<<(EE + 255) / 256, 256, 0, stream>>>(ei, deg);
  scan1_k<<<NB, 256, 0, stream>>>(deg, incl, partial);
  scan2_k<<<1, 256, 0, stream>>>(partial);
  scan3_k<<<NB, 256, 0, stream>>>(deg, incl, partial, rowptr, cursor);
  scatter_k<<<(EE + 255) / 256, 256, 0, stream>>>(ei, cursor, csr_src);

  auto run_layer = [&](const float* in, int K, const float* W, const float* a_s,
                       const float* a_d, const float* bias, int H, int Hsh,
                       float* hbuf, float* obuf, int do_relu) {
    int F = H * 64;
    dim3 gg((NN + 63) / 64, F / 64);
    gemm_k<<<gg, 256, 0, stream>>>(in, W, hbuf, K, F);
    alpha_k<<<(NN * H * 64 + 255) / 256, 256, 0, stream>>>(hbuf, a_s, a_d, als, ald, H, Hsh);
    gat_aggr_k<<<NN, F, 0, stream>>>(rowptr, deg, csr_src, als, ald, hbuf, bias, obuf, H, do_relu);
  };

  // layer 0: x[N,128] -> bufB[N,256], relu
  run_layer(x, 128, W0, a0s, a0d, b0, 4, 2, bufA, bufB, 1);
  // layer 1: bufB[N,256] -> bufB[N,256], relu
  run_layer(bufB, 256, W1, a1s, a1d, b1, 4, 2, bufA, bufB, 1);
  // layer 2: bufB[N,256] -> bufB[N,64], no relu
  run_layer(bufB, 256, W2, a2s, a2d, b2, 1, 0, bufA, bufB, 0);

  hipMemsetAsync(g, 0, 64 * 4, stream);
  colsum_k<<<256, 256, 0, stream>>>(bufB, g);
  head_k<<<1, 64, 0, stream>>>(g, hw, hb, out);
}

// Round 3
// 634.673 us; speedup vs baseline: 3.5462x; 1.5341x over previous
//
#include <hip/hip_runtime.h>
#include <hip/hip_bf16.h>
#include <cstddef>

#define NN 50000
#define EE 800000
#define NB ((NN + 255) / 256)

typedef __attribute__((ext_vector_type(8))) short short8;
typedef __attribute__((ext_vector_type(4))) float f32x4;

__device__ __forceinline__ float leaky(float x) { return x >= 0.f ? x : 0.2f * x; }
__device__ __forceinline__ float bf2f(unsigned short u) {
  return __uint_as_float(((unsigned int)u) << 16);
}
__device__ __forceinline__ unsigned short f2bf(float f) {
  __hip_bfloat16 b = __float2bfloat16(f);  // round-to-nearest
  return __builtin_bit_cast(unsigned short, b);
}

// ==== bf16 MFMA GEMM: C[m,n] = sum_k A[m,k]*Bt[n,k]; tile 128x64, 4 waves ====
// A: [M=NN][K] bf16 row-major. Bt: [Nfull][K] bf16 (pre-transposed weights).
// Cb: [NN][Nfull] bf16.
__global__ __launch_bounds__(256) void gemm_bf16_k(const unsigned short* __restrict__ A,
                                                   const unsigned short* __restrict__ Bt,
                                                   unsigned short* __restrict__ Cb,
                                                   int K, int Nfull) {
  // stride 40 shorts (80B): 16B-aligned rows, worst LDS aliasing 2-way (free)
  __shared__ __align__(16) unsigned short As[128 * 40];
  __shared__ __align__(16) unsigned short Bs[64 * 40];
  const int tid = threadIdx.x;
  const int lane = tid & 63;
  const int w = tid >> 6;
  const int bm = blockIdx.x * 128;
  const int bn = blockIdx.y * 64;
  const int quad = lane >> 4;
  const int l16 = lane & 15;
  f32x4 acc[2][4] = {};
  for (int kc = 0; kc < K; kc += 32) {
    // stage A tile 128x32 (each thread two 16B loads)
    {
      int row = tid >> 2, seg = tid & 3;
      int sr = bm + row; if (sr >= NN) sr = NN - 1;  // clamp: tail rows computed but unstored
      *(uint4*)&As[row * 40 + seg * 8] = *(const uint4*)(A + (size_t)sr * K + kc + seg * 8);
      row = (tid + 256) >> 2; seg = (tid + 256) & 3;
      sr = bm + row; if (sr >= NN) sr = NN - 1;
      *(uint4*)&As[row * 40 + seg * 8] = *(const uint4*)(A + (size_t)sr * K + kc + seg * 8);
      // stage Bt tile 64x32 (one 16B load/thread)
      int n = tid >> 2; seg = tid & 3;
      *(uint4*)&Bs[n * 40 + seg * 8] = *(const uint4*)(Bt + (size_t)(bn + n) * K + kc + seg * 8);
    }
    __syncthreads();
    // frags: A[m=lane&15][k=quad*8+j], B[n=lane&15][k=quad*8+j]
    short8 afr0 = *(const short8*)&As[(w * 32 + l16) * 40 + quad * 8];
    short8 afr1 = *(const short8*)&As[(w * 32 + 16 + l16) * 40 + quad * 8];
#pragma unroll
    for (int nt = 0; nt < 4; ++nt) {
      short8 bfr = *(const short8*)&Bs[(nt * 16 + l16) * 40 + quad * 8];
      acc[0][nt] = __builtin_amdgcn_mfma_f32_16x16x32_bf16(afr0, bfr, acc[0][nt], 0, 0, 0);
      acc[1][nt] = __builtin_amdgcn_mfma_f32_16x16x32_bf16(afr1, bfr, acc[1][nt], 0, 0, 0);
    }
    __syncthreads();
  }
  // epilogue: C/D layout col=lane&15, row=quad*4+reg
#pragma unroll
  for (int mt = 0; mt < 2; ++mt)
#pragma unroll
    for (int reg = 0; reg < 4; ++reg) {
      int r = bm + w * 32 + mt * 16 + quad * 4 + reg;
      if (r < NN) {
#pragma unroll
        for (int nt = 0; nt < 4; ++nt)
          Cb[(size_t)r * Nfull + bn + nt * 16 + l16] = f2bf(acc[mt][nt][reg]);
      }
    }
}

// ---- alpha_s/alpha_d from bf16 h: one wave per (node, head) ----
__global__ __launch_bounds__(256) void alpha_k(const unsigned short* __restrict__ h_b,
                                               const float* __restrict__ a_s,
                                               const float* __restrict__ a_d,
                                               float* __restrict__ als,
                                               float* __restrict__ ald,
                                               int H, int Hsh) {
  int gid = blockIdx.x * 256 + threadIdx.x;
  int wid = gid >> 6;
  int lane = gid & 63;
  if (wid >= NN * H) return;
  int hh = wid & (H - 1);
  int n = wid >> Hsh;
  float hv = bf2f(h_b[(size_t)n * (H << 6) + (hh << 6) + lane]);
  float va = hv * a_s[(hh << 6) + lane];
  float vd = hv * a_d[(hh << 6) + lane];
#pragma unroll
  for (int off = 32; off; off >>= 1) {
    va += __shfl_xor(va, off, 64);
    vd += __shfl_xor(vd, off, 64);
  }
  if (lane == 0) { als[wid] = va; ald[wid] = vd; }
}

// ================= CSR build (topology is layer-invariant) ==================
__global__ __launch_bounds__(256) void hist_k(const int* __restrict__ ei, int* deg) {
  int i = blockIdx.x * 256 + threadIdx.x;
  if (i < EE) atomicAdd(&deg[ei[EE + i]], 1);
}

__global__ __launch_bounds__(256) void scan1_k(const int* __restrict__ deg,
                                               int* __restrict__ incl,
                                               int* __restrict__ partial) {
  __shared__ int s[256];
  int t = threadIdx.x;
  int i = blockIdx.x * 256 + t;
  int v = (i < NN) ? deg[i] : 0;
  s[t] = v;
  __syncthreads();
  for (int off = 1; off < 256; off <<= 1) {
    int u = (t >= off) ? s[t - off] : 0;
    __syncthreads();
    s[t] += u;
    __syncthreads();
  }
  if (i < NN) incl[i] = s[t];
  if (t == 255) partial[blockIdx.x] = s[255];
}

__global__ void scan2_k(int* __restrict__ partial) {
  __shared__ int s[256];
  int t = threadIdx.x;
  int v = (t < NB) ? partial[t] : 0;
  s[t] = v;
  __syncthreads();
  for (int off = 1; off < 256; off <<= 1) {
    int u = (t >= off) ? s[t - off] : 0;
    __syncthreads();
    s[t] += u;
    __syncthreads();
  }
  if (t < NB) partial[t] = s[t] - v;  // exclusive
}

__global__ __launch_bounds__(256) void scan3_k(const int* __restrict__ deg,
                                               const int* __restrict__ incl,
                                               const int* __restrict__ partial,
                                               int* __restrict__ rowptr,
                                               int* __restrict__ cursor) {
  int i = blockIdx.x * 256 + threadIdx.x;
  if (i >= NN) return;
  int r = partial[blockIdx.x] + incl[i] - deg[i];
  rowptr[i] = r;
  cursor[i] = r;
}

__global__ __launch_bounds__(256) void scatter_k(const int* __restrict__ ei,
                                                 int* __restrict__ cursor,
                                                 int* __restrict__ csr_src) {
  int i = blockIdx.x * 256 + threadIdx.x;
  if (i >= EE) return;
  int d = ei[EE + i];
  int p = atomicAdd(&cursor[d], 1);
  csr_src[p] = ei[i];
}

// ====== fused softmax+aggregate, H=4: one block(128thr)/dst, 32 lanes/head ===
// h rows gathered as packed bf16 pairs (uint). Output packed bf16.
__global__ __launch_bounds__(128) void gat_aggr4_k(const int* __restrict__ rowptr,
                                                   const int* __restrict__ deg,
                                                   const int* __restrict__ csr_src,
                                                   const float* __restrict__ als,
                                                   const float* __restrict__ ald,
                                                   const unsigned int* __restrict__ hb_u,
                                                   const float* __restrict__ bias,
                                                   unsigned int* __restrict__ out_u) {
  int dst = blockIdx.x;
  int t = threadIdx.x;      // 0..127
  int head = t >> 5;
  int sub = t & 31;
  int rs = rowptr[dst];
  int dg = deg[dst];
  float aldv = ald[dst * 4 + head];
  float xself = leaky(als[dst * 4 + head] + aldv);

  float m = xself;
  for (int j = sub; j < dg; j += 32) {
    int s = csr_src[rs + j];
    m = fmaxf(m, leaky(als[s * 4 + head] + aldv));
  }
#pragma unroll
  for (int off = 16; off; off >>= 1) m = fmaxf(m, __shfl_xor(m, off, 64));

  float ssum = 0.f;
  for (int j = sub; j < dg; j += 32) {
    int s = csr_src[rs + j];
    ssum += __expf(leaky(als[s * 4 + head] + aldv) - m);
  }
#pragma unroll
  for (int off = 16; off; off >>= 1) ssum += __shfl_xor(ssum, off, 64);
  ssum += __expf(xself - m);
  float inv = 1.f / (ssum + 1e-16f);

  float aself = __expf(xself - m) * inv;
  unsigned int hv = hb_u[(size_t)dst * 128 + t];
  float acc0 = aself * __uint_as_float(hv << 16);
  float acc1 = aself * __uint_as_float(hv & 0xFFFF0000u);
  for (int j = 0; j < dg; ++j) {
    int s = csr_src[rs + j];
    float a = __expf(leaky(als[s * 4 + head] + aldv) - m) * inv;
    unsigned int v = hb_u[(size_t)s * 128 + t];
    acc0 += a * __uint_as_float(v << 16);
    acc1 += a * __uint_as_float(v & 0xFFFF0000u);
  }
  int c0 = head * 64 + sub * 2;
  float v0 = fmaxf(acc0 + bias[c0], 0.f);       // all H=4 layers have relu
  float v1 = fmaxf(acc1 + bias[c0 + 1], 0.f);
  out_u[(size_t)dst * 128 + t] = ((unsigned int)f2bf(v1) << 16) | f2bf(v0);
}

// ====== fused softmax+aggregate, H=1 (layer 2): one wave/dst, fp32 output ====
__global__ __launch_bounds__(64) void gat_aggr1_k(const int* __restrict__ rowptr,
                                                  const int* __restrict__ deg,
                                                  const int* __restrict__ csr_src,
                                                  const float* __restrict__ als,
                                                  const float* __restrict__ ald,
                                                  const unsigned short* __restrict__ hb,
                                                  const float* __restrict__ bias,
                                                  float* __restrict__ out) {
  int dst = blockIdx.x;
  int lane = threadIdx.x;
  int rs = rowptr[dst];
  int dg = deg[dst];
  float aldv = ald[dst];
  float xself = leaky(als[dst] + aldv);

  float m = xself;
  for (int j = lane; j < dg; j += 64) {
    int s = csr_src[rs + j];
    m = fmaxf(m, leaky(als[s] + aldv));
  }
#pragma unroll
  for (int off = 32; off; off >>= 1) m = fmaxf(m, __shfl_xor(m, off, 64));

  float ssum = 0.f;
  for (int j = lane; j < dg; j += 64) {
    int s = csr_src[rs + j];
    ssum += __expf(leaky(als[s] + aldv) - m);
  }
#pragma unroll
  for (int off = 32; off; off >>= 1) ssum += __shfl_xor(ssum, off, 64);
  ssum += __expf(xself - m);
  float inv = 1.f / (ssum + 1e-16f);

  float acc = __expf(xself - m) * inv * bf2f(hb[(size_t)dst * 64 + lane]);
  for (int j = 0; j < dg; ++j) {
    int s = csr_src[rs + j];
    float a = __expf(leaky(als[s] + aldv) - m) * inv;
    acc += a * bf2f(hb[(size_t)s * 64 + lane]);
  }
  out[(size_t)dst * 64 + lane] = acc + bias[lane];  // no relu on layer 2
}

// ---- prep: fp32 x -> packed bf16 ----
__global__ __launch_bounds__(256) void castx_k(const float2* __restrict__ x2,
                                               unsigned int* __restrict__ xb_u) {
  int i = blockIdx.x * 256 + threadIdx.x;
  if (i >= NN * 64) return;  // NN*128/2
  float2 v = x2[i];
  xb_u[i] = ((unsigned int)f2bf(v.y) << 16) | f2bf(v.x);
}

// ---- prep: W[K][N] fp32 -> Wt[N][K] bf16 ----
__global__ __launch_bounds__(64) void trw_k(const float* __restrict__ W,
                                            unsigned short* __restrict__ Wt, int K, int N) {
  int k = blockIdx.x;
  int n = blockIdx.y * 64 + threadIdx.x;
  Wt[(size_t)n * K + k] = f2bf(W[(size_t)k * N + n]);
}

// column sums of final [N,64] fp32 -> g[64]
__global__ __launch_bounds__(256) void colsum_k(const float* __restrict__ h2,
                                                float* __restrict__ g) {
  __shared__ float s[256];
  int tid = threadIdx.x;
  int c = tid & 63, rg = tid >> 6;
  float acc = 0.f;
  for (int n = blockIdx.x * 4 + rg; n < NN; n += gridDim.x * 4)
    acc += h2[n * 64 + c];
  s[tid] = acc;
  __syncthreads();
  if (tid < 64) atomicAdd(&g[c], s[c] + s[64 + c] + s[128 + c] + s[192 + c]);
}

__global__ void head_k(const float* __restrict__ g, const float* __restrict__ hw,
                       const float* __restrict__ hb, float* __restrict__ out) {
  int o = threadIdx.x;  // 64 threads
  float acc = 0.f;
  const float invN = 1.0f / (float)NN;
#pragma unroll 8
  for (int c = 0; c < 64; ++c) acc += (g[c] * invN) * hw[c * 64 + o];
  out[o] = acc + hb[o];
}

extern "C" void kernel_launch(void* const* d_in, const int* in_sizes, int n_in,
                              void* d_out, int out_size, void* d_ws, size_t ws_size,
                              hipStream_t stream) {
  const float* x   = (const float*)d_in[0];
  const int*   ei  = (const int*)d_in[1];
  const float* W0  = (const float*)d_in[2];
  const float* a0s = (const float*)d_in[3];
  const float* a0d = (const float*)d_in[4];
  const float* b0  = (const float*)d_in[5];
  const float* W1  = (const float*)d_in[6];
  const float* a1s = (const float*)d_in[7];
  const float* a1d = (const float*)d_in[8];
  const float* b1  = (const float*)d_in[9];
  const float* W2  = (const float*)d_in[10];
  const float* a2s = (const float*)d_in[11];
  const float* a2d = (const float*)d_in[12];
  const float* b2  = (const float*)d_in[13];
  const float* hw  = (const float*)d_in[14];
  const float* hb  = (const float*)d_in[15];
  float* out = (float*)d_out;

  char* w = (char*)d_ws;
  unsigned short* xb   = (unsigned short*)w; w += (size_t)NN * 128 * 2;  // 12.8 MB
  unsigned short* bufG = (unsigned short*)w; w += (size_t)NN * 256 * 2;  // gemm out, 25.6 MB
  unsigned short* bufA = (unsigned short*)w; w += (size_t)NN * 256 * 2;  // aggr out, 25.6 MB
  float* bufF = (float*)w;                   w += (size_t)NN * 64 * 4;   // final fp32, 12.8 MB
  unsigned short* W0t = (unsigned short*)w;  w += 256 * 128 * 2;
  unsigned short* W1t = (unsigned short*)w;  w += 256 * 256 * 2;
  unsigned short* W2t = (unsigned short*)w;  w += 64 * 256 * 2;
  float* als  = (float*)w;    w += (size_t)NN * 4 * 4;
  float* ald  = (float*)w;    w += (size_t)NN * 4 * 4;
  int* deg     = (int*)w;     w += (size_t)NN * 4;
  int* rowptr  = (int*)w;     w += (size_t)NN * 4;
  int* cursor  = (int*)w;     w += (size_t)NN * 4;
  int* incl    = (int*)w;     w += (size_t)NN * 4;
  int* partial = (int*)w;     w += 256 * 4;
  int* csr_src = (int*)w;     w += (size_t)EE * 4;
  float* g    = (float*)w;    w += 256;

  // ---- CSR build (shared by all 3 layers) ----
  hipMemsetAsync(deg, 0, (size_t)NN * 4, stream);
  hist_k<<<(EE + 255) / 256, 256, 0, stream>>>(ei, deg);
  scan1_k<<<NB, 256, 0, stream>>>(deg, incl, partial);
  scan2_k<<<1, 256, 0, stream>>>(partial);
  scan3_k<<<NB, 256, 0, stream>>>(deg, incl, partial, rowptr, cursor);
  scatter_k<<<(EE + 255) / 256, 256, 0, stream>>>(ei, cursor, csr_src);

  // ---- prep casts/transposes ----
  castx_k<<<(NN * 64 + 255) / 256, 256, 0, stream>>>((const float2*)x, (unsigned int*)xb);
  trw_k<<<dim3(128, 4), 64, 0, stream>>>(W0, W0t, 128, 256);
  trw_k<<<dim3(256, 4), 64, 0, stream>>>(W1, W1t, 256, 256);
  trw_k<<<dim3(256, 1), 64, 0, stream>>>(W2, W2t, 256, 64);

  const int GX = (NN + 127) / 128;

  // layer 0: xb[N,128] @ W0 -> bufG[N,256]; aggr -> bufA (bf16, relu)
  gemm_bf16_k<<<dim3(GX, 4), 256, 0, stream>>>(xb, W0t, bufG, 128, 256);
  alpha_k<<<(NN * 4 * 64 + 255) / 256, 256, 0, stream>>>(bufG, a0s, a0d, als, ald, 4, 2);
  gat_aggr4_k<<<NN, 128, 0, stream>>>(rowptr, deg, csr_src, als, ald,
                                      (const unsigned int*)bufG, b0, (unsigned int*)bufA);

  // layer 1: bufA @ W1 -> bufG[N,256]; aggr -> bufA (bf16, relu)
  gemm_bf16_k<<<dim3(GX, 4), 256, 0, stream>>>(bufA, W1t, bufG, 256, 256);
  alpha_k<<<(NN * 4 * 64 + 255) / 256, 256, 0, stream>>>(bufG, a1s, a1d, als, ald, 4, 2);
  gat_aggr4_k<<<NN, 128, 0, stream>>>(rowptr, deg, csr_src, als, ald,
                                      (const unsigned int*)bufG, b1, (unsigned int*)bufA);

  // layer 2: bufA @ W2 -> bufG[N,64]; aggr -> bufF (fp32, no relu)
  gemm_bf16_k<<<dim3(GX, 1), 256, 0, stream>>>(bufA, W2t, bufG, 256, 64);
  alpha_k<<<(NN * 64 + 255) / 256, 256, 0, stream>>>(bufG, a2s, a2d, als, ald, 1, 0);
  gat_aggr1_k<<<NN, 64, 0, stream>>>(rowptr, deg, csr_src, als, ald, bufG, b2, bufF);

  hipMemsetAsync(g, 0, 64 * 4, stream);
  colsum_k<<<256, 256, 0, stream>>>(bufF, g);
  head_k<<<1, 64, 0, stream>>>(g, hw, hb, out);
}

// Round 4
// 534.648 us; speedup vs baseline: 4.2097x; 1.1871x over previous
//
#include <hip/hip_runtime.h>
#include <hip/hip_bf16.h>
#include <cstddef>

#define NN 50000
#define EE 800000
#define NB ((NN + 255) / 256)

typedef __attribute__((ext_vector_type(8))) short short8;
typedef __attribute__((ext_vector_type(4))) float f32x4;

__device__ __forceinline__ float leaky(float x) { return x >= 0.f ? x : 0.2f * x; }
__device__ __forceinline__ float bf2f(unsigned short u) {
  return __uint_as_float(((unsigned int)u) << 16);
}
__device__ __forceinline__ float bflo(unsigned int v) { return __uint_as_float(v << 16); }
__device__ __forceinline__ float bfhi(unsigned int v) { return __uint_as_float(v & 0xFFFF0000u); }
__device__ __forceinline__ unsigned short f2bf(float f) {
  __hip_bfloat16 b = __float2bfloat16(f);  // round-to-nearest
  return __builtin_bit_cast(unsigned short, b);
}

// ==== bf16 MFMA GEMM: C[m,n] = sum_k A[m,k]*Bt[n,k]; tile 128x64, 4 waves ====
__global__ __launch_bounds__(256) void gemm_bf16_k(const unsigned short* __restrict__ A,
                                                   const unsigned short* __restrict__ Bt,
                                                   unsigned short* __restrict__ Cb,
                                                   int K, int Nfull) {
  __shared__ __align__(16) unsigned short As[128 * 40];
  __shared__ __align__(16) unsigned short Bs[64 * 40];
  const int tid = threadIdx.x;
  const int lane = tid & 63;
  const int w = tid >> 6;
  const int bm = blockIdx.x * 128;
  const int bn = blockIdx.y * 64;
  const int quad = lane >> 4;
  const int l16 = lane & 15;
  f32x4 acc[2][4] = {};
  for (int kc = 0; kc < K; kc += 32) {
    {
      int row = tid >> 2, seg = tid & 3;
      int sr = bm + row; if (sr >= NN) sr = NN - 1;
      *(uint4*)&As[row * 40 + seg * 8] = *(const uint4*)(A + (size_t)sr * K + kc + seg * 8);
      row = (tid + 256) >> 2; seg = (tid + 256) & 3;
      sr = bm + row; if (sr >= NN) sr = NN - 1;
      *(uint4*)&As[row * 40 + seg * 8] = *(const uint4*)(A + (size_t)sr * K + kc + seg * 8);
      int n = tid >> 2; seg = tid & 3;
      *(uint4*)&Bs[n * 40 + seg * 8] = *(const uint4*)(Bt + (size_t)(bn + n) * K + kc + seg * 8);
    }
    __syncthreads();
    short8 afr0 = *(const short8*)&As[(w * 32 + l16) * 40 + quad * 8];
    short8 afr1 = *(const short8*)&As[(w * 32 + 16 + l16) * 40 + quad * 8];
#pragma unroll
    for (int nt = 0; nt < 4; ++nt) {
      short8 bfr = *(const short8*)&Bs[(nt * 16 + l16) * 40 + quad * 8];
      acc[0][nt] = __builtin_amdgcn_mfma_f32_16x16x32_bf16(afr0, bfr, acc[0][nt], 0, 0, 0);
      acc[1][nt] = __builtin_amdgcn_mfma_f32_16x16x32_bf16(afr1, bfr, acc[1][nt], 0, 0, 0);
    }
    __syncthreads();
  }
#pragma unroll
  for (int mt = 0; mt < 2; ++mt)
#pragma unroll
    for (int reg = 0; reg < 4; ++reg) {
      int r = bm + w * 32 + mt * 16 + quad * 4 + reg;
      if (r < NN) {
#pragma unroll
        for (int nt = 0; nt < 4; ++nt)
          Cb[(size_t)r * Nfull + bn + nt * 16 + l16] = f2bf(acc[mt][nt][reg]);
      }
    }
}

// ---- alpha_s/alpha_d from bf16 h: one wave per (node, head) ----
__global__ __launch_bounds__(256) void alpha_k(const unsigned short* __restrict__ h_b,
                                               const float* __restrict__ a_s,
                                               const float* __restrict__ a_d,
                                               float* __restrict__ als,
                                               float* __restrict__ ald,
                                               int H, int Hsh) {
  int gid = blockIdx.x * 256 + threadIdx.x;
  int wid = gid >> 6;
  int lane = gid & 63;
  if (wid >= NN * H) return;
  int hh = wid & (H - 1);
  int n = wid >> Hsh;
  float hv = bf2f(h_b[(size_t)n * (H << 6) + (hh << 6) + lane]);
  float va = hv * a_s[(hh << 6) + lane];
  float vd = hv * a_d[(hh << 6) + lane];
#pragma unroll
  for (int off = 32; off; off >>= 1) {
    va += __shfl_xor(va, off, 64);
    vd += __shfl_xor(vd, off, 64);
  }
  if (lane == 0) { als[wid] = va; ald[wid] = vd; }
}

// ================= CSR build (topology is layer-invariant) ==================
__global__ __launch_bounds__(256) void hist_k(const int* __restrict__ ei, int* deg) {
  int i = blockIdx.x * 256 + threadIdx.x;
  if (i < EE) atomicAdd(&deg[ei[EE + i]], 1);
}

__global__ __launch_bounds__(256) void scan1_k(const int* __restrict__ deg,
                                               int* __restrict__ incl,
                                               int* __restrict__ partial) {
  __shared__ int s[256];
  int t = threadIdx.x;
  int i = blockIdx.x * 256 + t;
  int v = (i < NN) ? deg[i] : 0;
  s[t] = v;
  __syncthreads();
  for (int off = 1; off < 256; off <<= 1) {
    int u = (t >= off) ? s[t - off] : 0;
    __syncthreads();
    s[t] += u;
    __syncthreads();
  }
  if (i < NN) incl[i] = s[t];
  if (t == 255) partial[blockIdx.x] = s[255];
}

__global__ void scan2_k(int* __restrict__ partial) {
  __shared__ int s[256];
  int t = threadIdx.x;
  int v = (t < NB) ? partial[t] : 0;
  s[t] = v;
  __syncthreads();
  for (int off = 1; off < 256; off <<= 1) {
    int u = (t >= off) ? s[t - off] : 0;
    __syncthreads();
    s[t] += u;
    __syncthreads();
  }
  if (t < NB) partial[t] = s[t] - v;  // exclusive
}

__global__ __launch_bounds__(256) void scan3_k(const int* __restrict__ deg,
                                               const int* __restrict__ incl,
                                               const int* __restrict__ partial,
                                               int* __restrict__ rowptr,
                                               int* __restrict__ cursor) {
  int i = blockIdx.x * 256 + threadIdx.x;
  if (i >= NN) return;
  int r = partial[blockIdx.x] + incl[i] - deg[i];
  rowptr[i] = r;
  cursor[i] = r;
}

__global__ __launch_bounds__(256) void scatter_k(const int* __restrict__ ei,
                                                 int* __restrict__ cursor,
                                                 int* __restrict__ csr_src) {
  int i = blockIdx.x * 256 + threadIdx.x;
  if (i >= EE) return;
  int d = ei[EE + i];
  int p = atomicAdd(&cursor[d], 1);
  csr_src[p] = ei[i];
}

// ====== fused softmax+aggregate, H=4: one wave/dst, 4 dst per 256-block ======
// phases A/B: 16 lanes/head. phase C: half-wave = one 512B row (uint4/lane),
// two edges in flight per wave.
__global__ __launch_bounds__(256) void gat_aggr4_k(const int* __restrict__ rowptr,
                                                   const int* __restrict__ deg,
                                                   const int* __restrict__ csr_src,
                                                   const float* __restrict__ als,
                                                   const float* __restrict__ ald,
                                                   const uint4* __restrict__ hb4,
                                                   const float* __restrict__ bias,
                                                   uint4* __restrict__ out4) {
  const int dst = blockIdx.x * 4 + (threadIdx.x >> 6);
  const int lane = threadIdx.x & 63;
  const int rs = rowptr[dst];
  const int dg = deg[dst];

  // ---- phases A/B: head = lane>>4, jj = lane&15 ----
  const int headAB = lane >> 4;
  const int jj = lane & 15;
  const float aldv = ald[dst * 4 + headAB];
  const float xself = leaky(als[dst * 4 + headAB] + aldv);

  float m = xself;
  for (int j = jj; j < dg; j += 16) {
    int s = csr_src[rs + j];
    m = fmaxf(m, leaky(als[s * 4 + headAB] + aldv));
  }
#pragma unroll
  for (int off = 1; off < 16; off <<= 1) m = fmaxf(m, __shfl_xor(m, off, 64));

  float ssum = 0.f;
  for (int j = jj; j < dg; j += 16) {
    int s = csr_src[rs + j];
    ssum += __expf(leaky(als[s * 4 + headAB] + aldv) - m);
  }
#pragma unroll
  for (int off = 1; off < 16; off <<= 1) ssum += __shfl_xor(ssum, off, 64);
  ssum += __expf(xself - m);
  const float inv = 1.f / (ssum + 1e-16f);

  // ---- redistribute to phase-C layout: cidx = lane&31 (uint4 in row) ----
  const int cidx = lane & 31;
  const int half = lane >> 5;
  const int srcLane = (cidx >> 3) << 4;  // head_c * 16
  const float m_c = __shfl(m, srcLane, 64);
  const float inv_c = __shfl(inv, srcLane, 64);
  const float aldv_c = __shfl(aldv, srcLane, 64);
  const float xself_c = __shfl(xself, srcLane, 64);
  const int head_c = cidx >> 3;

  float acc[8] = {};
  if (half == 0) {  // self-loop contribution counted once
    float a = __expf(xself_c - m_c) * inv_c;
    uint4 v = hb4[(size_t)dst * 32 + cidx];
    acc[0] += a * bflo(v.x); acc[1] += a * bfhi(v.x);
    acc[2] += a * bflo(v.y); acc[3] += a * bfhi(v.y);
    acc[4] += a * bflo(v.z); acc[5] += a * bfhi(v.z);
    acc[6] += a * bflo(v.w); acc[7] += a * bfhi(v.w);
  }
  for (int j = half; j < dg; j += 2) {
    int s = csr_src[rs + j];
    float a = __expf(leaky(als[s * 4 + head_c] + aldv_c) - m_c) * inv_c;
    uint4 v = hb4[(size_t)s * 32 + cidx];
    acc[0] += a * bflo(v.x); acc[1] += a * bfhi(v.x);
    acc[2] += a * bflo(v.y); acc[3] += a * bfhi(v.y);
    acc[4] += a * bflo(v.z); acc[5] += a * bfhi(v.z);
    acc[6] += a * bflo(v.w); acc[7] += a * bfhi(v.w);
  }
#pragma unroll
  for (int k = 0; k < 8; ++k) acc[k] += __shfl_xor(acc[k], 32, 64);

  if (half == 0) {
    const float4 bz0 = *(const float4*)(bias + cidx * 8);
    const float4 bz1 = *(const float4*)(bias + cidx * 8 + 4);
    float v0 = fmaxf(acc[0] + bz0.x, 0.f), v1 = fmaxf(acc[1] + bz0.y, 0.f);
    float v2 = fmaxf(acc[2] + bz0.z, 0.f), v3 = fmaxf(acc[3] + bz0.w, 0.f);
    float v4 = fmaxf(acc[4] + bz1.x, 0.f), v5 = fmaxf(acc[5] + bz1.y, 0.f);
    float v6 = fmaxf(acc[6] + bz1.z, 0.f), v7 = fmaxf(acc[7] + bz1.w, 0.f);
    uint4 o;
    o.x = ((unsigned int)f2bf(v1) << 16) | f2bf(v0);
    o.y = ((unsigned int)f2bf(v3) << 16) | f2bf(v2);
    o.z = ((unsigned int)f2bf(v5) << 16) | f2bf(v4);
    o.w = ((unsigned int)f2bf(v7) << 16) | f2bf(v6);
    out4[(size_t)dst * 32 + cidx] = o;
  }
}

// ====== fused softmax+aggregate, H=1: one wave/dst, 8 edges in flight ========
// slot = lane>>3 (edge), c8 = lane&7 (uint4 within the 128B row).
__global__ __launch_bounds__(256) void gat_aggr1_k(const int* __restrict__ rowptr,
                                                   const int* __restrict__ deg,
                                                   const int* __restrict__ csr_src,
                                                   const float* __restrict__ als,
                                                   const float* __restrict__ ald,
                                                   const uint4* __restrict__ hb4,
                                                   const float* __restrict__ bias,
                                                   float* __restrict__ out) {
  const int dst = blockIdx.x * 4 + (threadIdx.x >> 6);
  const int lane = threadIdx.x & 63;
  const int rs = rowptr[dst];
  const int dg = deg[dst];
  const float aldv = ald[dst];
  const float xself = leaky(als[dst] + aldv);

  float m = xself;
  for (int j = lane; j < dg; j += 64) {
    int s = csr_src[rs + j];
    m = fmaxf(m, leaky(als[s] + aldv));
  }
#pragma unroll
  for (int off = 32; off; off >>= 1) m = fmaxf(m, __shfl_xor(m, off, 64));

  float ssum = 0.f;
  for (int j = lane; j < dg; j += 64) {
    int s = csr_src[rs + j];
    ssum += __expf(leaky(als[s] + aldv) - m);
  }
#pragma unroll
  for (int off = 32; off; off >>= 1) ssum += __shfl_xor(ssum, off, 64);
  ssum += __expf(xself - m);
  const float inv = 1.f / (ssum + 1e-16f);

  const int slot = lane >> 3;
  const int c8 = lane & 7;
  float acc[8] = {};
  if (slot == 0) {
    float a = __expf(xself - m) * inv;
    uint4 v = hb4[(size_t)dst * 8 + c8];
    acc[0] += a * bflo(v.x); acc[1] += a * bfhi(v.x);
    acc[2] += a * bflo(v.y); acc[3] += a * bfhi(v.y);
    acc[4] += a * bflo(v.z); acc[5] += a * bfhi(v.z);
    acc[6] += a * bflo(v.w); acc[7] += a * bfhi(v.w);
  }
  for (int j = slot; j < dg; j += 8) {
    int s = csr_src[rs + j];
    float a = __expf(leaky(als[s] + aldv) - m) * inv;
    uint4 v = hb4[(size_t)s * 8 + c8];
    acc[0] += a * bflo(v.x); acc[1] += a * bfhi(v.x);
    acc[2] += a * bflo(v.y); acc[3] += a * bfhi(v.y);
    acc[4] += a * bflo(v.z); acc[5] += a * bfhi(v.z);
    acc[6] += a * bflo(v.w); acc[7] += a * bfhi(v.w);
  }
#pragma unroll
  for (int k = 0; k < 8; ++k) {
    acc[k] += __shfl_xor(acc[k], 8, 64);
    acc[k] += __shfl_xor(acc[k], 16, 64);
    acc[k] += __shfl_xor(acc[k], 32, 64);
  }
  if (slot == 0) {  // no relu on layer 2; fp32 out
    const float4 bz0 = *(const float4*)(bias + c8 * 8);
    const float4 bz1 = *(const float4*)(bias + c8 * 8 + 4);
    float4 o0 = make_float4(acc[0] + bz0.x, acc[1] + bz0.y, acc[2] + bz0.z, acc[3] + bz0.w);
    float4 o1 = make_float4(acc[4] + bz1.x, acc[5] + bz1.y, acc[6] + bz1.z, acc[7] + bz1.w);
    *(float4*)(out + (size_t)dst * 64 + c8 * 8) = o0;
    *(float4*)(out + (size_t)dst * 64 + c8 * 8 + 4) = o1;
  }
}

// ---- prep: fp32 x -> packed bf16 ----
__global__ __launch_bounds__(256) void castx_k(const float2* __restrict__ x2,
                                               unsigned int* __restrict__ xb_u) {
  int i = blockIdx.x * 256 + threadIdx.x;
  if (i >= NN * 64) return;
  float2 v = x2[i];
  xb_u[i] = ((unsigned int)f2bf(v.y) << 16) | f2bf(v.x);
}

// ---- prep: W[K][N] fp32 -> Wt[N][K] bf16 ----
__global__ __launch_bounds__(64) void trw_k(const float* __restrict__ W,
                                            unsigned short* __restrict__ Wt, int K, int N) {
  int k = blockIdx.x;
  int n = blockIdx.y * 64 + threadIdx.x;
  Wt[(size_t)n * K + k] = f2bf(W[(size_t)k * N + n]);
}

// column sums of final [N,64] fp32 -> g[64]
__global__ __launch_bounds__(256) void colsum_k(const float* __restrict__ h2,
                                                float* __restrict__ g) {
  __shared__ float s[256];
  int tid = threadIdx.x;
  int c = tid & 63, rg = tid >> 6;
  float acc = 0.f;
  for (int n = blockIdx.x * 4 + rg; n < NN; n += gridDim.x * 4)
    acc += h2[n * 64 + c];
  s[tid] = acc;
  __syncthreads();
  if (tid < 64) atomicAdd(&g[c], s[c] + s[64 + c] + s[128 + c] + s[192 + c]);
}

__global__ void head_k(const float* __restrict__ g, const float* __restrict__ hw,
                       const float* __restrict__ hb, float* __restrict__ out) {
  int o = threadIdx.x;  // 64 threads
  float acc = 0.f;
  const float invN = 1.0f / (float)NN;
#pragma unroll 8
  for (int c = 0; c < 64; ++c) acc += (g[c] * invN) * hw[c * 64 + o];
  out[o] = acc + hb[o];
}

extern "C" void kernel_launch(void* const* d_in, const int* in_sizes, int n_in,
                              void* d_out, int out_size, void* d_ws, size_t ws_size,
                              hipStream_t stream) {
  const float* x   = (const float*)d_in[0];
  const int*   ei  = (const int*)d_in[1];
  const float* W0  = (const float*)d_in[2];
  const float* a0s = (const float*)d_in[3];
  const float* a0d = (const float*)d_in[4];
  const float* b0  = (const float*)d_in[5];
  const float* W1  = (const float*)d_in[6];
  const float* a1s = (const float*)d_in[7];
  const float* a1d = (const float*)d_in[8];
  const float* b1  = (const float*)d_in[9];
  const float* W2  = (const float*)d_in[10];
  const float* a2s = (const float*)d_in[11];
  const float* a2d = (const float*)d_in[12];
  const float* b2  = (const float*)d_in[13];
  const float* hw  = (const float*)d_in[14];
  const float* hb  = (const float*)d_in[15];
  float* out = (float*)d_out;

  char* w = (char*)d_ws;
  unsigned short* xb   = (unsigned short*)w; w += (size_t)NN * 128 * 2;
  unsigned short* bufG = (unsigned short*)w; w += (size_t)NN * 256 * 2;
  unsigned short* bufA = (unsigned short*)w; w += (size_t)NN * 256 * 2;
  float* bufF = (float*)w;                   w += (size_t)NN * 64 * 4;
  unsigned short* W0t = (unsigned short*)w;  w += 256 * 128 * 2;
  unsigned short* W1t = (unsigned short*)w;  w += 256 * 256 * 2;
  unsigned short* W2t = (unsigned short*)w;  w += 64 * 256 * 2;
  float* als  = (float*)w;    w += (size_t)NN * 4 * 4;
  float* ald  = (float*)w;    w += (size_t)NN * 4 * 4;
  int* deg     = (int*)w;     w += (size_t)NN * 4;
  int* rowptr  = (int*)w;     w += (size_t)NN * 4;
  int* cursor  = (int*)w;     w += (size_t)NN * 4;
  int* incl    = (int*)w;     w += (size_t)NN * 4;
  int* partial = (int*)w;     w += 256 * 4;
  int* csr_src = (int*)w;     w += (size_t)EE * 4;
  float* g    = (float*)w;    w += 256;

  // ---- CSR build (shared by all 3 layers) ----
  hipMemsetAsync(deg, 0, (size_t)NN * 4, stream);
  hist_k<<<(EE + 255) / 256, 256, 0, stream>>>(ei, deg);
  scan1_k<<<NB, 256, 0, stream>>>(deg, incl, partial);
  scan2_k<<<1, 256, 0, stream>>>(partial);
  scan3_k<<<NB, 256, 0, stream>>>(deg, incl, partial, rowptr, cursor);
  scatter_k<<<(EE + 255) / 256, 256, 0, stream>>>(ei, cursor, csr_src);

  // ---- prep casts/transposes ----
  castx_k<<<(NN * 64 + 255) / 256, 256, 0, stream>>>((const float2*)x, (unsigned int*)xb);
  trw_k<<<dim3(128, 4), 64, 0, stream>>>(W0, W0t, 128, 256);
  trw_k<<<dim3(256, 4), 64, 0, stream>>>(W1, W1t, 256, 256);
  trw_k<<<dim3(256, 1), 64, 0, stream>>>(W2, W2t, 256, 64);

  const int GX = (NN + 127) / 128;
  const int GA = NN / 4;  // 12500, exact

  // layer 0
  gemm_bf16_k<<<dim3(GX, 4), 256, 0, stream>>>(xb, W0t, bufG, 128, 256);
  alpha_k<<<(NN * 4 * 64 + 255) / 256, 256, 0, stream>>>(bufG, a0s, a0d, als, ald, 4, 2);
  gat_aggr4_k<<<GA, 256, 0, stream>>>(rowptr, deg, csr_src, als, ald,
                                      (const uint4*)bufG, b0, (uint4*)bufA);
  // layer 1
  gemm_bf16_k<<<dim3(GX, 4), 256, 0, stream>>>(bufA, W1t, bufG, 256, 256);
  alpha_k<<<(NN * 4 * 64 + 255) / 256, 256, 0, stream>>>(bufG, a1s, a1d, als, ald, 4, 2);
  gat_aggr4_k<<<GA, 256, 0, stream>>>(rowptr, deg, csr_src, als, ald,
                                      (const uint4*)bufG, b1, (uint4*)bufA);
  // layer 2
  gemm_bf16_k<<<dim3(GX, 1), 256, 0, stream>>>(bufA, W2t, bufG, 256, 64);
  alpha_k<<<(NN * 64 + 255) / 256, 256, 0, stream>>>(bufG, a2s, a2d, als, ald, 1, 0);
  gat_aggr1_k<<<GA, 256, 0, stream>>>(rowptr, deg, csr_src, als, ald,
                                      (const uint4*)bufG, b2, bufF);

  hipMemsetAsync(g, 0, 64 * 4, stream);
  colsum_k<<<256, 256, 0, stream>>>(bufF, g);
  head_k<<<1, 64, 0, stream>>>(g, hw, hb, out);
}